// Round 18
// baseline (37.897 us; speedup 1.0000x reference)
//
#include <hip/hip_runtime.h>
#include <hip/hip_bf16.h>

// out[b, f*64+n] = sum_c sum_j x[b, c*64+j] * w[f, c, (n-j)&63]
// R15: SINGLE fused kernel. Fixed-cost accounting (R7/R8/R10/R13 cross-checks)
// shows 2 launches + pack ~ 10.4us of the 19.7 -- the K-loop was never the
// whole story. Block reads its 32 A-rows directly from x (fp32, 2xfloat4 per
// fragment, cvt_pk_bf16 in-register, RNE = same absmax); pack kernel and Xp
// round-trip deleted. Else R14: 256 blk (8q x 32fg, q=XCD) x 1024 thr,
// 16 waves = 2cg(f) x 8kg(c-group), circulant tables in LDS (147456B),
// mfma 32x32x16, flat 2-barrier epilogue.

#define KDIM 4096

typedef __attribute__((ext_vector_type(8)))  short s16x8;
typedef __attribute__((ext_vector_type(4)))  float f32x4;
typedef __attribute__((ext_vector_type(16))) float f32x16;
typedef unsigned short u16;

__device__ __forceinline__ u16 f2bf(float f) {
  unsigned int u = __float_as_uint(f);
  u += 0x7FFF + ((u >> 16) & 1);   // round-to-nearest-even
  return (u16)(u >> 16);
}

// 8 consecutive fp32 -> s16x8 bf16 (RNE via v_cvt_pk_bf16_f32)
__device__ __forceinline__ s16x8 cvt8(float4 lo, float4 hi) {
  union { __hip_bfloat162 h[4]; s16x8 v; } u;
  u.h[0] = __float22bfloat162_rn(make_float2(lo.x, lo.y));
  u.h[1] = __float22bfloat162_rn(make_float2(lo.z, lo.w));
  u.h[2] = __float22bfloat162_rn(make_float2(hi.x, hi.y));
  u.h[3] = __float22bfloat162_rn(make_float2(hi.z, hi.w));
  return u.v;
}

__global__ __launch_bounds__(1024, 4) void gemm_fused(const float* __restrict__ x,
                                                      const float* __restrict__ w,
                                                      float* __restrict__ out) {
  extern __shared__ __align__(16) char pool[];   // 147456 B
  u16*   tab = (u16*)pool;                       // [2f][64c][576] u16
  float* red = (float*)pool;                     // epilogue: 16 slots x 8 KB

  const int tid   = threadIdx.x;
  const int lane  = tid & 63;
  const int wid   = tid >> 6;        // 0..15 = kg*2 + cg
  const int cg    = wid & 1;         // which f of the pair
  const int kg    = wid >> 1;        // K-group: c in [kg*8, kg*8+8)
  const int l31   = lane & 31;
  const int lh    = lane >> 5;
  const int q     = blockIdx.x & 7;  // 32-row group; == XCD id (x-slice L2-local)
  const int fg    = blockIdx.x >> 3; // f-pair index (0..31)

  // ---- build 128 circulant tables: wave wid builds t = wid*8 .. wid*8+7 ----
  // t = fidx*64 + c ; table: C_m[i] = bf16(w[f][c][(-i-m)&63]), stride 72 u16
  #pragma unroll
  for (int j = 0; j < 8; ++j) {
    int t    = wid * 8 + j;
    int fidx = t >> 6;
    int c    = t & 63;
    u16 bv = f2bf(w[((size_t)(fg * 2 + fidx) << 12) + (c << 6) + lane]);
    u16* T = tab + t * 576;
    #pragma unroll
    for (int m = 0; m < 8; ++m) {
      int i = (-(lane + m)) & 63;
      T[m * 72 + i] = bv;
    }
  }

  int bofs0, bofs1, bofs2, bofs3;
  {
    int i0;
    i0 = (lh * 8 - l31)      & 63; bofs0 = (i0 & 7) * 71 + i0;
    i0 = (lh * 8 - l31 - 16) & 63; bofs1 = (i0 & 7) * 71 + i0;
    i0 = (lh * 8 - l31 - 32) & 63; bofs2 = (i0 & 7) * 71 + i0;
    i0 = (lh * 8 - l31 - 48) & 63; bofs3 = (i0 & 7) * 71 + i0;
  }

  // A source: lane reads x[q*32 + l31][c*64 + kk*16 + lh*8 + 0..7] (fp32)
  const float* xrow = x + ((size_t)(q * 32 + l31) << 12) + lh * 8;
  const u16*   tabf = tab + cg * 36864;   // this wave's f-table block (64*576)

  f32x16 acc0 = {}, acc1 = {};

  __syncthreads();                   // tables visible

  #pragma unroll
  for (int T = 0; T < 8; ++T) {
    const float* xs = xrow + ((kg * 8 + T) << 6);
    s16x8 a0 = cvt8(*(const float4*)(xs +  0), *(const float4*)(xs +  4));
    s16x8 a1 = cvt8(*(const float4*)(xs + 16), *(const float4*)(xs + 20));
    s16x8 a2 = cvt8(*(const float4*)(xs + 32), *(const float4*)(xs + 36));
    s16x8 a3 = cvt8(*(const float4*)(xs + 48), *(const float4*)(xs + 52));
    const u16* Tb = tabf + (kg * 8 + T) * 576;
    s16x8 b0 = *(const s16x8*)(Tb + bofs0);
    s16x8 b1 = *(const s16x8*)(Tb + bofs1);
    s16x8 b2 = *(const s16x8*)(Tb + bofs2);
    s16x8 b3 = *(const s16x8*)(Tb + bofs3);
    // pairing (R5-verified): acc0 uses b[(0-kk)&3], acc1 uses b[(2-kk)&3]
    acc0 = __builtin_amdgcn_mfma_f32_32x32x16_bf16(a0, b0, acc0, 0, 0, 0);
    acc1 = __builtin_amdgcn_mfma_f32_32x32x16_bf16(a0, b2, acc1, 0, 0, 0);
    acc0 = __builtin_amdgcn_mfma_f32_32x32x16_bf16(a1, b3, acc0, 0, 0, 0);
    acc1 = __builtin_amdgcn_mfma_f32_32x32x16_bf16(a1, b1, acc1, 0, 0, 0);
    acc0 = __builtin_amdgcn_mfma_f32_32x32x16_bf16(a2, b2, acc0, 0, 0, 0);
    acc1 = __builtin_amdgcn_mfma_f32_32x32x16_bf16(a2, b0, acc1, 0, 0, 0);
    acc0 = __builtin_amdgcn_mfma_f32_32x32x16_bf16(a3, b1, acc0, 0, 0, 0);
    acc1 = __builtin_amdgcn_mfma_f32_32x32x16_bf16(a3, b3, acc1, 0, 0, 0);
  }

  // ---- flattened epilogue: 2 barriers; 8-way kgroup reduce per cg ----
  __syncthreads();                   // all table reads done; reuse pool
  {
    float* slot = red + (cg * 8 + kg) * 2048;   // 8 KB per wave
    #pragma unroll
    for (int i = 0; i < 4; ++i) {
      f32x4 v0 = {acc0[4*i], acc0[4*i+1], acc0[4*i+2], acc0[4*i+3]};
      f32x4 v1 = {acc1[4*i], acc1[4*i+1], acc1[4*i+2], acc1[4*i+3]};
      *(f32x4*)(slot + ((i)     * 64 + lane) * 4) = v0;
      *(f32x4*)(slot + ((i + 4) * 64 + lane) * 4) = v1;
    }
  }
  __syncthreads();
  {
    const int rcg = tid >> 9;            // which f of the pair we reduce
    const int ii  = (tid >> 6) & 7;      // 0..3 acc0 quads, 4..7 acc1 quads
    const int sl  = tid & 63;            // source lane
    f32x4 s = {};
    #pragma unroll
    for (int k = 0; k < 8; ++k)
      s += *(const f32x4*)(red + (size_t)(rcg * 8 + k) * 2048 + (ii * 64 + sl) * 4);
    // C/D (m74/m101): col = lane&31, row = (reg&3)+8*(reg>>2)+4*(lane>>5)
    const int col  = ((fg * 2 + rcg) << 6) + (ii >> 2) * 32 + (sl & 31);
    const int rowb = q * 32 + 8 * (ii & 3) + 4 * (sl >> 5);
    #pragma unroll
    for (int e = 0; e < 4; ++e)
      out[(size_t)(rowb + e) * 4096 + col] = s[e];
  }
}

extern "C" void kernel_launch(void* const* d_in, const int* in_sizes, int n_in,
                              void* d_out, int out_size, void* d_ws, size_t ws_size,
                              hipStream_t stream) {
  const float* x = (const float*)d_in[0];    // (256, 4096) fp32
  const float* w = (const float*)d_in[1];    // (64, 64, 64) fp32
  float* out = (float*)d_out;                // (256, 4096) fp32

  gemm_fused<<<256, 1024, 147456, stream>>>(x, w, out);
}